// Round 4
// baseline (1306.708 us; speedup 1.0000x reference)
//
#include <hip/hip_runtime.h>
#include <hip/hip_bf16.h>
#include <stdint.h>

// ---------------------------------------------------------------------------
// MoE dense:  B=4 T=2048 D=1024 H=2048 E=8
// R3: ALL tensors fp32 (inputs and output), per the reference dtypes.
//   Evidence: R1 (bf16-read) -> NaN  == fp32 data read as bf16 pairs.
//             R2 (fp32-read, bf16-out) -> absmax 0.773 == bf16 output read
//             as fp32 by the harness (flat[i] ~ out[2i+1]).
// Compute path: fp32 -> bf16 MFMA (fp32 accum). Predicted absmax ~1.5e-3
// vs threshold 1.21e-2 (2% of refmax) -- 8x margin.
//
// ws layout (bytes):
//   gate  fp32 [8192,8]   @ 0        256 KiB
//   W1t_e bf16 [H,D]      @ 1  MiB   4 MiB   (per-expert, reused)
//   W2t_e bf16 [D,H]      @ 5  MiB   4 MiB   (per-expert, reused)
//   hg_e  bf16 [8192,H]   @ 9  MiB   32 MiB  (per-expert, reused)
// total 41 MiB (73 MiB proven non-faulting in R1/R2)
// ---------------------------------------------------------------------------

typedef __bf16 bf16_t;
typedef bf16_t bf16x8 __attribute__((ext_vector_type(8)));
typedef bf16_t bf16x4 __attribute__((ext_vector_type(4)));
typedef float  f32x4  __attribute__((ext_vector_type(4)));

#define Bdim 4
#define Tdim 2048
#define Ddim 1024
#define Hdim 2048
#define Edim 8
#define Mdim (Bdim*Tdim)   // 8192

// ---------------- gating: one wave per token ------------------------------
__global__ void gating_kernel(const float* __restrict__ x,
                              const float* __restrict__ Wg,
                              const float* __restrict__ bg,
                              float* __restrict__ gate) {
  const int lane = threadIdx.x & 63;
  const int wid  = threadIdx.x >> 6;
  const int t    = blockIdx.x * 4 + wid;
  const float* xr = x + (size_t)t * Ddim;
  float acc[8] = {0.f,0.f,0.f,0.f,0.f,0.f,0.f,0.f};
  for (int i = lane; i < Ddim; i += 64) {
    float xv = xr[i];
    f32x4 a = *(const f32x4*)(Wg + (size_t)i * 8);
    f32x4 b = *(const f32x4*)(Wg + (size_t)i * 8 + 4);
    acc[0] += xv * a[0]; acc[1] += xv * a[1];
    acc[2] += xv * a[2]; acc[3] += xv * a[3];
    acc[4] += xv * b[0]; acc[5] += xv * b[1];
    acc[6] += xv * b[2]; acc[7] += xv * b[3];
  }
  #pragma unroll
  for (int e = 0; e < 8; ++e) {
    #pragma unroll
    for (int off = 32; off; off >>= 1)
      acc[e] += __shfl_xor(acc[e], off, 64);
  }
  if (lane == 0) {
    float l[8], mx = -1e30f;
    #pragma unroll
    for (int e = 0; e < 8; ++e) { l[e] = acc[e] + bg[e]; mx = fmaxf(mx, l[e]); }
    float s = 0.f;
    #pragma unroll
    for (int e = 0; e < 8; ++e) { l[e] = __expf(l[e] - mx); s += l[e]; }
    float inv = 1.f / s;
    #pragma unroll
    for (int e = 0; e < 8; ++e) gate[(size_t)t * 8 + e] = l[e] * inv;
  }
}

// ------- transpose [R,C] fp32 -> [C,R] bf16 -------------------------------
__global__ void transpose_f32_bf16(const float* __restrict__ src,
                                   bf16_t* __restrict__ dst, int R, int C) {
  __shared__ bf16_t tile[32][33];
  const int r0 = blockIdx.y * 32, c0 = blockIdx.x * 32;
  const int tr = threadIdx.x >> 3;          // 0..31
  const int tc = (threadIdx.x & 7) * 4;     // 0..28 step 4
  f32x4 v = *(const f32x4*)(src + (size_t)(r0 + tr) * C + c0 + tc);
  tile[tr][tc+0] = (bf16_t)v[0]; tile[tr][tc+1] = (bf16_t)v[1];
  tile[tr][tc+2] = (bf16_t)v[2]; tile[tr][tc+3] = (bf16_t)v[3];
  __syncthreads();
  bf16x4 o;
  o[0] = tile[tc+0][tr]; o[1] = tile[tc+1][tr];
  o[2] = tile[tc+2][tr]; o[3] = tile[tc+3][tr];
  *(bf16x4*)(dst + (size_t)(c0 + tr) * R + r0 + tc) = o;
}

// ---------------- 128x128 GEMM, A[M,K] x Bt[N,K], ds_write staging --------
// MODE 1: A = x (fp32, cvt->bf16 in staging); out: hg bf16 = g*relu(acc+b1)
// MODE 2: A = hg (bf16);                      out: fp32 += acc + g*b2
template <int MODE>
__launch_bounds__(256, 2)
__global__ void gemm_moe(const float*  __restrict__ Af,
                         const bf16_t* __restrict__ Abf,
                         const bf16_t* __restrict__ Bt,
                         const float*  __restrict__ gate,
                         const float*  __restrict__ bias,   // already +e*stride
                         bf16_t* __restrict__ outBf,
                         float*  __restrict__ outF32,
                         int K, int e) {
  __shared__ alignas(16) bf16_t sA[128 * 32];
  __shared__ alignas(16) bf16_t sB[128 * 32];

  const int tid  = threadIdx.x;
  const int lane = tid & 63;
  const int wid  = tid >> 6;
  const int wm   = wid >> 1, wn = wid & 1;      // 2x2 waves -> 64x64 each
  const int lrow = lane & 15, quad = lane >> 4;

  const int tileN = blockIdx.x * 128;
  const int tileM = blockIdx.y * 128;

  // staging: thread t -> row = t>>1, 16-element k-chunk at (t&1)*16
  const int srow = tid >> 1;
  const int sk   = (tid & 1) * 16;

  f32x4 acc[4][4] = {};

  for (int kk = 0; kk < K; kk += 32) {
    // ---- global loads into registers ----
    bf16x8 a0, a1;
    if (MODE == 1) {
      const float* p = Af + (size_t)(tileM + srow) * K + kk + sk;
      f32x4 f0 = *(const f32x4*)(p);
      f32x4 f1 = *(const f32x4*)(p + 4);
      f32x4 f2 = *(const f32x4*)(p + 8);
      f32x4 f3 = *(const f32x4*)(p + 12);
      #pragma unroll
      for (int j = 0; j < 4; ++j) { a0[j] = (bf16_t)f0[j]; a0[4+j] = (bf16_t)f1[j]; }
      #pragma unroll
      for (int j = 0; j < 4; ++j) { a1[j] = (bf16_t)f2[j]; a1[4+j] = (bf16_t)f3[j]; }
    } else {
      const bf16_t* p = Abf + (size_t)(tileM + srow) * K + kk + sk;
      a0 = *(const bf16x8*)(p);
      a1 = *(const bf16x8*)(p + 8);
    }
    const bf16_t* q = Bt + (size_t)(tileN + srow) * K + kk + sk;
    bf16x8 b0 = *(const bf16x8*)(q);
    bf16x8 b1 = *(const bf16x8*)(q + 8);

    __syncthreads();                  // prior-iter LDS frag reads complete
    *(bf16x8*)&sA[srow * 32 + sk]     = a0;
    *(bf16x8*)&sA[srow * 32 + sk + 8] = a1;
    *(bf16x8*)&sB[srow * 32 + sk]     = b0;
    *(bf16x8*)&sB[srow * 32 + sk + 8] = b1;
    __syncthreads();                  // staging visible to all waves

    bf16x8 af[4], bfr[4];
    #pragma unroll
    for (int i = 0; i < 4; ++i)
      af[i] = *(const bf16x8*)&sA[(wm * 64 + i * 16 + lrow) * 32 + quad * 8];
    #pragma unroll
    for (int j = 0; j < 4; ++j)
      bfr[j] = *(const bf16x8*)&sB[(wn * 64 + j * 16 + lrow) * 32 + quad * 8];
    #pragma unroll
    for (int i = 0; i < 4; ++i)
      #pragma unroll
      for (int j = 0; j < 4; ++j)
        acc[i][j] = __builtin_amdgcn_mfma_f32_16x16x32_bf16(af[i], bfr[j], acc[i][j], 0, 0, 0);
  }

  // epilogue: C/D layout col=lane&15, row=quad*4+reg  [verified m89/m91]
  float bcol[4];
  #pragma unroll
  for (int j = 0; j < 4; ++j)
    bcol[j] = bias[tileN + wn * 64 + j * 16 + lrow];

  #pragma unroll
  for (int i = 0; i < 4; ++i) {
    #pragma unroll
    for (int r = 0; r < 4; ++r) {
      const int row = tileM + wm * 64 + i * 16 + quad * 4 + r;
      const float g = gate[(size_t)row * 8 + e];
      #pragma unroll
      for (int j = 0; j < 4; ++j) {
        const int col = tileN + wn * 64 + j * 16 + lrow;
        if (MODE == 1) {
          float v = acc[i][j][r] + bcol[j];
          v = fmaxf(v, 0.f) * g;
          outBf[(size_t)row * Hdim + col] = (bf16_t)v;
        } else {
          float v = acc[i][j][r] + g * bcol[j];
          outF32[(size_t)row * Ddim + col] += v;
        }
      }
    }
  }
}

extern "C" void kernel_launch(void* const* d_in, const int* in_sizes, int n_in,
                              void* d_out, int out_size, void* d_ws, size_t ws_size,
                              hipStream_t stream) {
  const float* x  = (const float*)d_in[0];
  const float* Wg = (const float*)d_in[1];
  const float* bg = (const float*)d_in[2];
  const float* W1 = (const float*)d_in[3];
  const float* b1 = (const float*)d_in[4];
  const float* W2 = (const float*)d_in[5];
  const float* b2 = (const float*)d_in[6];
  float* out = (float*)d_out;

  char* ws = (char*)d_ws;
  float*  gate = (float*)ws;                      // 256 KiB
  bf16_t* W1t  = (bf16_t*)(ws + (1u << 20));      // 4 MiB (per-expert)
  bf16_t* W2t  = (bf16_t*)(ws + (5u << 20));      // 4 MiB (per-expert)
  bf16_t* hg   = (bf16_t*)(ws + (9u << 20));      // 32 MiB (per-expert)

  gating_kernel<<<Mdim / 4, 256, 0, stream>>>(x, Wg, bg, gate);
  // d_out is poisoned before every timed launch -> zero it (we accumulate).
  hipMemsetAsync(out, 0, (size_t)Mdim * Ddim * sizeof(float), stream);

  for (int e = 0; e < Edim; ++e) {
    const float* W1e = W1 + (size_t)e * Ddim * Hdim;   // [D,H]
    const float* W2e = W2 + (size_t)e * Hdim * Ddim;   // [H,D]

    // W1[e]: [D,H] -> W1t [H,D] bf16
    transpose_f32_bf16<<<dim3(Hdim / 32, Ddim / 32), 256, 0, stream>>>(
        W1e, W1t, Ddim, Hdim);
    // W2[e]: [H,D] -> W2t [D,H] bf16
    transpose_f32_bf16<<<dim3(Ddim / 32, Hdim / 32), 256, 0, stream>>>(
        W2e, W2t, Hdim, Ddim);

    // hg = gate_e * relu(x @ W1[e] + b1[e])    (M=8192, N=2048, K=1024)
    gemm_moe<1><<<dim3(Hdim / 128, Mdim / 128), 256, 0, stream>>>(
        x, nullptr, W1t, gate, b1 + (size_t)e * Hdim, hg, nullptr, Ddim, e);

    // out += hg @ W2[e] + gate_e * b2[e]       (M=8192, N=1024, K=2048)
    gemm_moe<2><<<dim3(Ddim / 128, Mdim / 128), 256, 0, stream>>>(
        nullptr, hg, W2t, gate, b2 + (size_t)e * Ddim, nullptr, out, Hdim, e);
  }
}

// Round 5
// 978.690 us; speedup vs baseline: 1.3352x; 1.3352x over previous
//
#include <hip/hip_runtime.h>
#include <hip/hip_bf16.h>
#include <stdint.h>

// ---------------------------------------------------------------------------
// MoE dense:  B=4 T=2048 D=1024 H=2048 E=8   (fp32 in/out, bf16 MFMA compute)
// R5: m97-style global_load_lds staging (16B) + x pre-converted to bf16 +
// XCD-aware block swizzle. Per-expert sequential pipeline (ws = 57 MiB).
//
// ws layout (bytes):
//   gate fp32 [8192,8]    @ 0        256 KiB
//   xb   bf16 [8192,1024] @ 1  MiB   16 MiB
//   W1t  bf16 [H,D]       @ 17 MiB   4 MiB   (per-expert, reused)
//   W2t  bf16 [D,H]       @ 21 MiB   4 MiB   (per-expert, reused)
//   hg   bf16 [8192,H]    @ 25 MiB   32 MiB  (per-expert, reused)
// total 57 MiB  (<= 73 MiB proven non-faulting)
// ---------------------------------------------------------------------------

typedef __bf16 bf16_t;
typedef bf16_t bf16x8 __attribute__((ext_vector_type(8)));
typedef bf16_t bf16x4 __attribute__((ext_vector_type(4)));
typedef float  f32x4  __attribute__((ext_vector_type(4)));

#define Ddim 1024
#define Hdim 2048
#define Edim 8
#define Mdim 8192

__device__ __forceinline__ void async16(const void* g, const void* l) {
  __builtin_amdgcn_global_load_lds(
      (const __attribute__((address_space(1))) void*)(uintptr_t)g,
      (__attribute__((address_space(3))) void*)(uint32_t)(uintptr_t)l,
      16, 0, 0);
}

// ---------------- gating: one wave per token (verified R4) ----------------
__global__ void gating_kernel(const float* __restrict__ x,
                              const float* __restrict__ Wg,
                              const float* __restrict__ bg,
                              float* __restrict__ gate) {
  const int lane = threadIdx.x & 63;
  const int wid  = threadIdx.x >> 6;
  const int t    = blockIdx.x * 4 + wid;
  const float* xr = x + (size_t)t * Ddim;
  float acc[8] = {0.f,0.f,0.f,0.f,0.f,0.f,0.f,0.f};
  for (int i = lane; i < Ddim; i += 64) {
    float xv = xr[i];
    f32x4 a = *(const f32x4*)(Wg + (size_t)i * 8);
    f32x4 b = *(const f32x4*)(Wg + (size_t)i * 8 + 4);
    acc[0] += xv * a[0]; acc[1] += xv * a[1];
    acc[2] += xv * a[2]; acc[3] += xv * a[3];
    acc[4] += xv * b[0]; acc[5] += xv * b[1];
    acc[6] += xv * b[2]; acc[7] += xv * b[3];
  }
  #pragma unroll
  for (int e = 0; e < 8; ++e) {
    #pragma unroll
    for (int off = 32; off; off >>= 1)
      acc[e] += __shfl_xor(acc[e], off, 64);
  }
  if (lane == 0) {
    float l[8], mx = -1e30f;
    #pragma unroll
    for (int e = 0; e < 8; ++e) { l[e] = acc[e] + bg[e]; mx = fmaxf(mx, l[e]); }
    float s = 0.f;
    #pragma unroll
    for (int e = 0; e < 8; ++e) { l[e] = __expf(l[e] - mx); s += l[e]; }
    float inv = 1.f / s;
    #pragma unroll
    for (int e = 0; e < 8; ++e) gate[(size_t)t * 8 + e] = l[e] * inv;
  }
}

// ---------------- x fp32 -> bf16 (contiguous) -----------------------------
__global__ void cvt_x(const float* __restrict__ a, bf16_t* __restrict__ o) {
  const size_t i = ((size_t)blockIdx.x * 256 + threadIdx.x) * 8;
  f32x4 v0 = *(const f32x4*)(a + i);
  f32x4 v1 = *(const f32x4*)(a + i + 4);
  bf16x8 b;
  b[0]=(bf16_t)v0[0]; b[1]=(bf16_t)v0[1]; b[2]=(bf16_t)v0[2]; b[3]=(bf16_t)v0[3];
  b[4]=(bf16_t)v1[0]; b[5]=(bf16_t)v1[1]; b[6]=(bf16_t)v1[2]; b[7]=(bf16_t)v1[3];
  *(bf16x8*)(o + i) = b;
}

// ------- transpose [R,C] fp32 -> [C,R] bf16 (verified R4) -----------------
__global__ void transpose_f32_bf16(const float* __restrict__ src,
                                   bf16_t* __restrict__ dst, int R, int C) {
  __shared__ bf16_t tile[32][33];
  const int r0 = blockIdx.y * 32, c0 = blockIdx.x * 32;
  const int tr = threadIdx.x >> 3;
  const int tc = (threadIdx.x & 7) * 4;
  f32x4 v = *(const f32x4*)(src + (size_t)(r0 + tr) * C + c0 + tc);
  tile[tr][tc+0] = (bf16_t)v[0]; tile[tr][tc+1] = (bf16_t)v[1];
  tile[tr][tc+2] = (bf16_t)v[2]; tile[tr][tc+3] = (bf16_t)v[3];
  __syncthreads();
  bf16x4 o;
  o[0] = tile[tc+0][tr]; o[1] = tile[tc+1][tr];
  o[2] = tile[tc+2][tr]; o[3] = tile[tc+3][tr];
  *(bf16x4*)(dst + (size_t)(c0 + tr) * R + r0 + tc) = o;
}

// ---------------- 128x128 GEMM, A[M,K] x Bt[N,K], async LDS staging -------
// MODE 1: hg[row*H + col]  = bf16( gate[row,e] * relu(acc + bias[col]) )
// MODE 2: out[row*D + col] += acc + gate[row,e] * bias[col]      (fp32 RMW)
// LBX: log2(gridDim.x) for the XCD swizzle (gridDim.y must be 64).
template <int MODE, int LBX>
__launch_bounds__(256, 2)
__global__ void gemm_moe(const bf16_t* __restrict__ A,
                         const bf16_t* __restrict__ Bt,
                         const float*  __restrict__ gate,
                         const float*  __restrict__ bias,   // pre-offset +e*N
                         bf16_t* __restrict__ outBf,
                         float*  __restrict__ outF32,
                         int K, int e) {
  __shared__ alignas(16) bf16_t sA[128 * 32];
  __shared__ alignas(16) bf16_t sB[128 * 32];

  const int tid  = threadIdx.x;
  const int lane = tid & 63;
  const int wid  = tid >> 6;
  const int wm   = wid >> 1, wn = wid & 1;      // 2x2 waves, 64x64 each
  const int lrow = lane & 15, quad = lane >> 4;

  // XCD swizzle: each XCD (bid%8) owns a contiguous 8-tile M-range x all N,
  // so A-tiles are fetched ~once into one XCD's L2 (B is small, 4 MiB).
  const int bid = blockIdx.y * (1 << LBX) + blockIdx.x;
  const int xcd = bid & 7;
  const int loc = bid >> 3;
  const int by  = xcd * 8 + (loc >> LBX);
  const int bx  = loc & ((1 << LBX) - 1);
  const int tileN = bx * 128;
  const int tileM = by * 128;

  // staging: LDS tile [128 rows][32 k] bf16 = 8 KiB; 256 thr x 16 B x 2
  const int lb0 = tid * 16;
  const int lb1 = 4096 + tid * 16;
  const int r0 = lb0 >> 6, kb0 = lb0 & 63;
  const int r1 = lb1 >> 6, kb1 = lb1 & 63;

  const char* ap0 = (const char*)(A  + (size_t)(tileM + r0) * K) + kb0;
  const char* ap1 = (const char*)(A  + (size_t)(tileM + r1) * K) + kb1;
  const char* bp0 = (const char*)(Bt + (size_t)(tileN + r0) * K) + kb0;
  const char* bp1 = (const char*)(Bt + (size_t)(tileN + r1) * K) + kb1;
  const char* la0  = (const char*)sA + lb0;
  const char* la1  = (const char*)sA + lb1;
  const char* lbp0 = (const char*)sB + lb0;
  const char* lbp1 = (const char*)sB + lb1;

  f32x4 acc[4][4] = {};

  const int nIter = K >> 5;
  for (int it = 0; it < nIter; ++it) {
    __syncthreads();                  // prior-iter LDS frag reads complete
    async16(ap0, la0);
    async16(ap1, la1);
    async16(bp0, lbp0);
    async16(bp1, lbp1);
    ap0 += 64; ap1 += 64; bp0 += 64; bp1 += 64;
    __syncthreads();                  // drains vmcnt -> staging visible

    bf16x8 af[4], bfr[4];
    #pragma unroll
    for (int i = 0; i < 4; ++i)
      af[i] = *(const bf16x8*)&sA[(wm * 64 + i * 16 + lrow) * 32 + quad * 8];
    #pragma unroll
    for (int j = 0; j < 4; ++j)
      bfr[j] = *(const bf16x8*)&sB[(wn * 64 + j * 16 + lrow) * 32 + quad * 8];
    #pragma unroll
    for (int i = 0; i < 4; ++i)
      #pragma unroll
      for (int j = 0; j < 4; ++j)
        acc[i][j] = __builtin_amdgcn_mfma_f32_16x16x32_bf16(af[i], bfr[j], acc[i][j], 0, 0, 0);
  }

  // epilogue: C/D layout col=lane&15, row=quad*4+reg  [verified R4]
  float bcol[4];
  #pragma unroll
  for (int j = 0; j < 4; ++j)
    bcol[j] = bias[tileN + wn * 64 + j * 16 + lrow];

  #pragma unroll
  for (int i = 0; i < 4; ++i) {
    #pragma unroll
    for (int r = 0; r < 4; ++r) {
      const int row = tileM + wm * 64 + i * 16 + quad * 4 + r;
      const float g = gate[(size_t)row * 8 + e];
      #pragma unroll
      for (int j = 0; j < 4; ++j) {
        const int col = tileN + wn * 64 + j * 16 + lrow;
        if (MODE == 1) {
          float v = acc[i][j][r] + bcol[j];
          v = fmaxf(v, 0.f) * g;
          outBf[(size_t)row * Hdim + col] = (bf16_t)v;
        } else {
          float v = acc[i][j][r] + g * bcol[j];
          outF32[(size_t)row * Ddim + col] += v;
        }
      }
    }
  }
}

extern "C" void kernel_launch(void* const* d_in, const int* in_sizes, int n_in,
                              void* d_out, int out_size, void* d_ws, size_t ws_size,
                              hipStream_t stream) {
  const float* x  = (const float*)d_in[0];
  const float* Wg = (const float*)d_in[1];
  const float* bg = (const float*)d_in[2];
  const float* W1 = (const float*)d_in[3];
  const float* b1 = (const float*)d_in[4];
  const float* W2 = (const float*)d_in[5];
  const float* b2 = (const float*)d_in[6];
  float* out = (float*)d_out;

  char* ws = (char*)d_ws;
  float*  gate = (float*)ws;                       // 256 KiB
  bf16_t* xb   = (bf16_t*)(ws + (1u  << 20));      // 16 MiB
  bf16_t* W1t  = (bf16_t*)(ws + (17u << 20));      // 4 MiB (per-expert)
  bf16_t* W2t  = (bf16_t*)(ws + (21u << 20));      // 4 MiB (per-expert)
  bf16_t* hg   = (bf16_t*)(ws + (25u << 20));      // 32 MiB (per-expert)

  gating_kernel<<<Mdim / 4, 256, 0, stream>>>(x, Wg, bg, gate);
  cvt_x<<<(Mdim * Ddim) / (256 * 8), 256, 0, stream>>>(x, xb);
  hipMemsetAsync(out, 0, (size_t)Mdim * Ddim * sizeof(float), stream);

  for (int e = 0; e < Edim; ++e) {
    const float* W1e = W1 + (size_t)e * Ddim * Hdim;   // [D,H]
    const float* W2e = W2 + (size_t)e * Hdim * Ddim;   // [H,D]

    transpose_f32_bf16<<<dim3(Hdim / 32, Ddim / 32), 256, 0, stream>>>(
        W1e, W1t, Ddim, Hdim);
    transpose_f32_bf16<<<dim3(Ddim / 32, Hdim / 32), 256, 0, stream>>>(
        W2e, W2t, Hdim, Ddim);

    // hg = gate_e * relu(xb @ W1t^T + b1[e])   (M=8192, N=2048, K=1024)
    gemm_moe<1, 4><<<dim3(Hdim / 128, Mdim / 128), 256, 0, stream>>>(
        xb, W1t, gate, b1 + (size_t)e * Hdim, hg, nullptr, Ddim, e);

    // out += hg @ W2t^T + gate_e * b2[e]       (M=8192, N=1024, K=2048)
    gemm_moe<2, 3><<<dim3(Ddim / 128, Mdim / 128), 256, 0, stream>>>(
        hg, W2t, gate, b2 + (size_t)e * Ddim, nullptr, out, Hdim, e);
  }
}

// Round 6
// 849.328 us; speedup vs baseline: 1.5385x; 1.1523x over previous
//
#include <hip/hip_runtime.h>
#include <hip/hip_bf16.h>
#include <stdint.h>

// ---------------------------------------------------------------------------
// MoE dense:  B=4 T=2048 D=1024 H=2048 E=8   (fp32 in/out, bf16 MFMA compute)
// R6: ws-adaptive expert grouping G in {8,4,2,1} chosen from ws_size
//     (R0 proved ws in [73,320) MB by faulting at 320; stop guessing).
//   - transposes batched per group (z grid)
//   - gemm1 z-batched over group (one dispatch per group)
//   - gemm2 K-fused over group (K = G*2048), FIRST group writes out directly
//     (no memset, no fp32 RMW for the first group)
//
// ws layout (MB): gate@0 (1), xb@1 (16), W1t@17 (4G), W2t@17+4G (4G),
//                 hg@17+8G (32G).  need = 17 + 40G MB.
// ---------------------------------------------------------------------------

typedef __bf16 bf16_t;
typedef bf16_t bf16x8 __attribute__((ext_vector_type(8)));
typedef bf16_t bf16x4 __attribute__((ext_vector_type(4)));
typedef float  f32x4  __attribute__((ext_vector_type(4)));

#define Ddim 1024
#define Hdim 2048
#define Edim 8
#define Mdim 8192

__device__ __forceinline__ void async16(const void* g, const void* l) {
  __builtin_amdgcn_global_load_lds(
      (const __attribute__((address_space(1))) void*)(uintptr_t)g,
      (__attribute__((address_space(3))) void*)(uint32_t)(uintptr_t)l,
      16, 0, 0);
}

// ---------------- gating: one wave per token (verified R4/R5) -------------
__global__ void gating_kernel(const float* __restrict__ x,
                              const float* __restrict__ Wg,
                              const float* __restrict__ bg,
                              float* __restrict__ gate) {
  const int lane = threadIdx.x & 63;
  const int wid  = threadIdx.x >> 6;
  const int t    = blockIdx.x * 4 + wid;
  const float* xr = x + (size_t)t * Ddim;
  float acc[8] = {0.f,0.f,0.f,0.f,0.f,0.f,0.f,0.f};
  for (int i = lane; i < Ddim; i += 64) {
    float xv = xr[i];
    f32x4 a = *(const f32x4*)(Wg + (size_t)i * 8);
    f32x4 b = *(const f32x4*)(Wg + (size_t)i * 8 + 4);
    acc[0] += xv * a[0]; acc[1] += xv * a[1];
    acc[2] += xv * a[2]; acc[3] += xv * a[3];
    acc[4] += xv * b[0]; acc[5] += xv * b[1];
    acc[6] += xv * b[2]; acc[7] += xv * b[3];
  }
  #pragma unroll
  for (int e = 0; e < 8; ++e) {
    #pragma unroll
    for (int off = 32; off; off >>= 1)
      acc[e] += __shfl_xor(acc[e], off, 64);
  }
  if (lane == 0) {
    float l[8], mx = -1e30f;
    #pragma unroll
    for (int e = 0; e < 8; ++e) { l[e] = acc[e] + bg[e]; mx = fmaxf(mx, l[e]); }
    float s = 0.f;
    #pragma unroll
    for (int e = 0; e < 8; ++e) { l[e] = __expf(l[e] - mx); s += l[e]; }
    float inv = 1.f / s;
    #pragma unroll
    for (int e = 0; e < 8; ++e) gate[(size_t)t * 8 + e] = l[e] * inv;
  }
}

// ---------------- x fp32 -> bf16 ------------------------------------------
__global__ void cvt_x(const float* __restrict__ a, bf16_t* __restrict__ o) {
  const size_t i = ((size_t)blockIdx.x * 256 + threadIdx.x) * 8;
  f32x4 v0 = *(const f32x4*)(a + i);
  f32x4 v1 = *(const f32x4*)(a + i + 4);
  bf16x8 b;
  b[0]=(bf16_t)v0[0]; b[1]=(bf16_t)v0[1]; b[2]=(bf16_t)v0[2]; b[3]=(bf16_t)v0[3];
  b[4]=(bf16_t)v1[0]; b[5]=(bf16_t)v1[1]; b[6]=(bf16_t)v1[2]; b[7]=(bf16_t)v1[3];
  *(bf16x8*)(o + i) = b;
}

// ------- batched transpose [R,C] fp32 -> [C,R] bf16, z = expert-in-group --
__global__ void transpose_f32_bf16(const float* __restrict__ src,
                                   bf16_t* __restrict__ dst, int R, int C) {
  __shared__ bf16_t tile[32][33];
  const size_t zo = (size_t)blockIdx.z * (size_t)R * C;
  src += zo; dst += zo;
  const int r0 = blockIdx.y * 32, c0 = blockIdx.x * 32;
  const int tr = threadIdx.x >> 3;
  const int tc = (threadIdx.x & 7) * 4;
  f32x4 v = *(const f32x4*)(src + (size_t)(r0 + tr) * C + c0 + tc);
  tile[tr][tc+0] = (bf16_t)v[0]; tile[tr][tc+1] = (bf16_t)v[1];
  tile[tr][tc+2] = (bf16_t)v[2]; tile[tr][tc+3] = (bf16_t)v[3];
  __syncthreads();
  bf16x4 o;
  o[0] = tile[tc+0][tr]; o[1] = tile[tc+1][tr];
  o[2] = tile[tc+2][tr]; o[3] = tile[tc+3][tr];
  *(bf16x4*)(dst + (size_t)(c0 + tr) * R + r0 + tc) = o;
}

// ---------------- GEMM1: hg[z] = gate_e * relu(xb @ W1t[z]^T + b1[e]) -----
// grid (Hdim/128, Mdim/128, G); K = Ddim.
__launch_bounds__(256, 2)
__global__ void gemm1_kernel(const bf16_t* __restrict__ A,        // xb [M,D]
                             const bf16_t* __restrict__ W1tAll,   // [G,H,D]
                             const float*  __restrict__ gate,
                             const float*  __restrict__ b1,       // [E,H]
                             bf16_t* __restrict__ hgAll,          // [G,M,H]
                             int e0) {
  __shared__ alignas(16) bf16_t sA[128 * 32];
  __shared__ alignas(16) bf16_t sB[128 * 32];

  const int tid  = threadIdx.x;
  const int lane = tid & 63;
  const int wid  = tid >> 6;
  const int wm   = wid >> 1, wn = wid & 1;
  const int lrow = lane & 15, quad = lane >> 4;

  const int z = blockIdx.z;
  const int e = e0 + z;
  const bf16_t* Bt = W1tAll + (size_t)z * Hdim * Ddim;
  bf16_t* hg = hgAll + (size_t)z * Mdim * Hdim;
  const float* bias = b1 + (size_t)e * Hdim;

  // XCD swizzle within the z-plane (gridDim.x = 16 -> LBX=4, gridDim.y = 64)
  const int bid = blockIdx.y * 16 + blockIdx.x;
  const int xcd = bid & 7;
  const int loc = bid >> 3;
  const int tileM = (xcd * 8 + (loc >> 4)) * 128;
  const int tileN = (loc & 15) * 128;

  const int lb0 = tid * 16;
  const int lb1 = 4096 + tid * 16;
  const int r0 = lb0 >> 6, kb0 = lb0 & 63;
  const int r1 = lb1 >> 6, kb1 = lb1 & 63;

  const char* ap0 = (const char*)(A  + (size_t)(tileM + r0) * Ddim) + kb0;
  const char* ap1 = (const char*)(A  + (size_t)(tileM + r1) * Ddim) + kb1;
  const char* bp0 = (const char*)(Bt + (size_t)(tileN + r0) * Ddim) + kb0;
  const char* bp1 = (const char*)(Bt + (size_t)(tileN + r1) * Ddim) + kb1;
  const char* la0  = (const char*)sA + lb0;
  const char* la1  = (const char*)sA + lb1;
  const char* lbp0 = (const char*)sB + lb0;
  const char* lbp1 = (const char*)sB + lb1;

  f32x4 acc[4][4] = {};

  for (int it = 0; it < (Ddim >> 5); ++it) {
    __syncthreads();
    async16(ap0, la0);
    async16(ap1, la1);
    async16(bp0, lbp0);
    async16(bp1, lbp1);
    ap0 += 64; ap1 += 64; bp0 += 64; bp1 += 64;
    __syncthreads();

    bf16x8 af[4], bfr[4];
    #pragma unroll
    for (int i = 0; i < 4; ++i)
      af[i] = *(const bf16x8*)&sA[(wm * 64 + i * 16 + lrow) * 32 + quad * 8];
    #pragma unroll
    for (int j = 0; j < 4; ++j)
      bfr[j] = *(const bf16x8*)&sB[(wn * 64 + j * 16 + lrow) * 32 + quad * 8];
    #pragma unroll
    for (int i = 0; i < 4; ++i)
      #pragma unroll
      for (int j = 0; j < 4; ++j)
        acc[i][j] = __builtin_amdgcn_mfma_f32_16x16x32_bf16(af[i], bfr[j], acc[i][j], 0, 0, 0);
  }

  float bcol[4];
  #pragma unroll
  for (int j = 0; j < 4; ++j)
    bcol[j] = bias[tileN + wn * 64 + j * 16 + lrow];

  #pragma unroll
  for (int i = 0; i < 4; ++i) {
    #pragma unroll
    for (int r = 0; r < 4; ++r) {
      const int row = tileM + wm * 64 + i * 16 + quad * 4 + r;
      const float g = gate[(size_t)row * 8 + e];
      #pragma unroll
      for (int j = 0; j < 4; ++j) {
        const int col = tileN + wn * 64 + j * 16 + lrow;
        float v = acc[i][j][r] + bcol[j];
        v = fmaxf(v, 0.f) * g;
        hg[(size_t)row * Hdim + col] = (bf16_t)v;
      }
    }
  }
}

// ---------------- GEMM2: out (+)= sum_g hg[g] @ W2t[g]^T + gate*b2 --------
// grid (Ddim/128, Mdim/128); K = G*Hdim, fused over the group's experts.
template <int G, bool FIRST>
__launch_bounds__(256, 2)
__global__ void gemm2_kernel(const bf16_t* __restrict__ hgAll,    // [G,M,H]
                             const bf16_t* __restrict__ W2tAll,   // [G,D,H]
                             const float*  __restrict__ gate,
                             const float*  __restrict__ b2,       // [E,D]
                             float* __restrict__ out,             // [M,D]
                             int e0) {
  __shared__ alignas(16) bf16_t sA[128 * 32];
  __shared__ alignas(16) bf16_t sB[128 * 32];

  const int tid  = threadIdx.x;
  const int lane = tid & 63;
  const int wid  = tid >> 6;
  const int wm   = wid >> 1, wn = wid & 1;
  const int lrow = lane & 15, quad = lane >> 4;

  // XCD swizzle (gridDim.x = 8 -> LBX=3, gridDim.y = 64)
  const int bid = blockIdx.y * 8 + blockIdx.x;
  const int xcd = bid & 7;
  const int loc = bid >> 3;
  const int tileM = (xcd * 8 + (loc >> 3)) * 128;
  const int tileN = (loc & 7) * 128;

  const int lb0 = tid * 16;
  const int lb1 = 4096 + tid * 16;
  const int r0 = lb0 >> 6, kb0 = lb0 & 63;
  const int r1 = lb1 >> 6, kb1 = lb1 & 63;

  const char* la0  = (const char*)sA + lb0;
  const char* la1  = (const char*)sA + lb1;
  const char* lbp0 = (const char*)sB + lb0;
  const char* lbp1 = (const char*)sB + lb1;

  f32x4 acc[4][4] = {};

  #pragma unroll
  for (int g = 0; g < G; ++g) {
    const bf16_t* Ag = hgAll  + (size_t)g * Mdim * Hdim;
    const bf16_t* Bg = W2tAll + (size_t)g * Ddim * Hdim;
    const char* ap0 = (const char*)(Ag + (size_t)(tileM + r0) * Hdim) + kb0;
    const char* ap1 = (const char*)(Ag + (size_t)(tileM + r1) * Hdim) + kb1;
    const char* bp0 = (const char*)(Bg + (size_t)(tileN + r0) * Hdim) + kb0;
    const char* bp1 = (const char*)(Bg + (size_t)(tileN + r1) * Hdim) + kb1;

    for (int it = 0; it < (Hdim >> 5); ++it) {
      __syncthreads();
      async16(ap0, la0);
      async16(ap1, la1);
      async16(bp0, lbp0);
      async16(bp1, lbp1);
      ap0 += 64; ap1 += 64; bp0 += 64; bp1 += 64;
      __syncthreads();

      bf16x8 af[4], bfr[4];
      #pragma unroll
      for (int i = 0; i < 4; ++i)
        af[i] = *(const bf16x8*)&sA[(wm * 64 + i * 16 + lrow) * 32 + quad * 8];
      #pragma unroll
      for (int j = 0; j < 4; ++j)
        bfr[j] = *(const bf16x8*)&sB[(wn * 64 + j * 16 + lrow) * 32 + quad * 8];
      #pragma unroll
      for (int i = 0; i < 4; ++i)
        #pragma unroll
        for (int j = 0; j < 4; ++j)
          acc[i][j] = __builtin_amdgcn_mfma_f32_16x16x32_bf16(af[i], bfr[j], acc[i][j], 0, 0, 0);
    }
  }

  // epilogue: add sum_g gate[row,e0+g]*b2[e0+g,col]
  float b2c[4][G];
  #pragma unroll
  for (int j = 0; j < 4; ++j) {
    const int col = tileN + wn * 64 + j * 16 + lrow;
    #pragma unroll
    for (int g = 0; g < G; ++g)
      b2c[j][g] = b2[(size_t)(e0 + g) * Ddim + col];
  }

  #pragma unroll
  for (int i = 0; i < 4; ++i) {
    #pragma unroll
    for (int r = 0; r < 4; ++r) {
      const int row = tileM + wm * 64 + i * 16 + quad * 4 + r;
      const float* gr = gate + (size_t)row * 8 + e0;
      float gv[G];
      #pragma unroll
      for (int g = 0; g < G; ++g) gv[g] = gr[g];
      #pragma unroll
      for (int j = 0; j < 4; ++j) {
        const int col = tileN + wn * 64 + j * 16 + lrow;
        float v = acc[i][j][r];
        #pragma unroll
        for (int g = 0; g < G; ++g) v += gv[g] * b2c[j][g];
        if (FIRST) out[(size_t)row * Ddim + col] = v;
        else       out[(size_t)row * Ddim + col] += v;
      }
    }
  }
}

extern "C" void kernel_launch(void* const* d_in, const int* in_sizes, int n_in,
                              void* d_out, int out_size, void* d_ws, size_t ws_size,
                              hipStream_t stream) {
  const float* x  = (const float*)d_in[0];
  const float* Wg = (const float*)d_in[1];
  const float* bg = (const float*)d_in[2];
  const float* W1 = (const float*)d_in[3];
  const float* b1 = (const float*)d_in[4];
  const float* W2 = (const float*)d_in[5];
  const float* b2 = (const float*)d_in[6];
  float* out = (float*)d_out;

  // ws-adaptive group size: need = 17 + 40G MB
  int G = 1;
  if      (ws_size >= (size_t)(17 + 40 * 8) << 20) G = 8;
  else if (ws_size >= (size_t)(17 + 40 * 4) << 20) G = 4;
  else if (ws_size >= (size_t)(17 + 40 * 2) << 20) G = 2;

  char* ws = (char*)d_ws;
  float*  gate = (float*)ws;                                     // 1 MB region
  bf16_t* xb   = (bf16_t*)(ws + (1u << 20));                     // 16 MB
  bf16_t* W1t  = (bf16_t*)(ws + (17u << 20));                    // 4G MB
  bf16_t* W2t  = (bf16_t*)(ws + ((size_t)(17 + 4 * G) << 20));   // 4G MB
  bf16_t* hg   = (bf16_t*)(ws + ((size_t)(17 + 8 * G) << 20));   // 32G MB

  gating_kernel<<<Mdim / 4, 256, 0, stream>>>(x, Wg, bg, gate);
  cvt_x<<<(Mdim * Ddim) / (256 * 8), 256, 0, stream>>>(x, xb);

  const int nGroups = Edim / G;
  for (int gi = 0; gi < nGroups; ++gi) {
    const int e0 = gi * G;
    // W1[e0..e0+G): [D,H] -> W1t [H,D] bf16  (batched over z)
    transpose_f32_bf16<<<dim3(Hdim / 32, Ddim / 32, G), 256, 0, stream>>>(
        W1 + (size_t)e0 * Ddim * Hdim, W1t, Ddim, Hdim);
    // W2[e0..e0+G): [H,D] -> W2t [D,H] bf16
    transpose_f32_bf16<<<dim3(Ddim / 32, Hdim / 32, G), 256, 0, stream>>>(
        W2 + (size_t)e0 * Hdim * Ddim, W2t, Hdim, Ddim);

    // hg[z] = gate_e * relu(xb @ W1t[z]^T + b1[e])  (one dispatch per group)
    gemm1_kernel<<<dim3(Hdim / 128, Mdim / 128, G), 256, 0, stream>>>(
        xb, W1t, gate, b1, hg, e0);

    // out (+)= sum_g hg[g] @ W2t[g]^T + gate*b2     (K fused = G*2048)
    const dim3 g2(Ddim / 128, Mdim / 128);
    const bool first = (gi == 0);
    if (G == 8)      gemm2_kernel<8, true ><<<g2, 256, 0, stream>>>(hg, W2t, gate, b2, out, e0);
    else if (G == 4) {
      if (first)     gemm2_kernel<4, true ><<<g2, 256, 0, stream>>>(hg, W2t, gate, b2, out, e0);
      else           gemm2_kernel<4, false><<<g2, 256, 0, stream>>>(hg, W2t, gate, b2, out, e0);
    } else if (G == 2) {
      if (first)     gemm2_kernel<2, true ><<<g2, 256, 0, stream>>>(hg, W2t, gate, b2, out, e0);
      else           gemm2_kernel<2, false><<<g2, 256, 0, stream>>>(hg, W2t, gate, b2, out, e0);
    } else {
      if (first)     gemm2_kernel<1, true ><<<g2, 256, 0, stream>>>(hg, W2t, gate, b2, out, e0);
      else           gemm2_kernel<1, false><<<g2, 256, 0, stream>>>(hg, W2t, gate, b2, out, e0);
    }
  }
}